// Round 11
// baseline (141.056 us; speedup 1.0000x reference)
//
#include <hip/hip_runtime.h>

typedef float f32x4  __attribute__((ext_vector_type(4)));
typedef float f32x16 __attribute__((ext_vector_type(16)));
typedef short s16x8  __attribute__((ext_vector_type(8)));
typedef unsigned int u32;
typedef unsigned int u32x4 __attribute__((ext_vector_type(4)));
typedef unsigned short u16;

#define LL 2048
#define DD 64
#define NITER 32
#define SC_OFF 4194304ull

struct SMem {
    u16 Khi[2][64][72];   // double-buffered K tile [key][d], bf16, 144B stride
    u16 VT [2][64][72];   // double-buffered V^T tile [d][key], bf16
    u16 P  [8][32][72];   // wave-private P [q][64 keys], 144B stride (16B aligned)
};

__device__ __forceinline__ u32 cvt_pk_bf16(float lo, float hi) {
    u32 r;
    asm("v_cvt_pk_bf16_f32 %0, %1, %2" : "=v"(r) : "v"(lo), "v"(hi));
    return r;
}

__global__ __launch_bounds__(512, 2)
void psam_kernel(const float* __restrict__ Qg0, const float* __restrict__ Kg0,
                 const float* __restrict__ Vg0, const int* __restrict__ Mg0,
                 float* __restrict__ out)
{
    __shared__ SMem sm;
    const int tid = threadIdx.x;
    const int w = tid >> 6, l = tid & 63;
    const int j31 = l & 31, h = l >> 5;   // lane index within 32, half-wave

    // XCD-aware swizzle: 256 blocks, 32/XCD -> each bh's 8 blocks share one L2
    const int bid = ((int)blockIdx.x & 7) * 32 + ((int)blockIdx.x >> 3);
    const int bh = bid >> 3;
    const int m0 = (bid & 7) << 8;        // q-row tile start (BM=256)
    const int bB = bh >> 4;               // batch index (H=16)

    const float* Kg = Kg0 + (size_t)bh * LL * DD;
    const float* Vg = Vg0 + (size_t)bh * LL * DD;
    const int*   Mg = Mg0 + (size_t)bB * LL;
    float* So = out + SC_OFF + (size_t)bh * LL * LL + (size_t)m0 * LL;
    float* Oo = out + ((size_t)bh * LL + m0) * DD;

    // ---------- Q fragments (A-operand), wave's own 32 q-rows ----------
    s16x8 qf[4];
    {
        const float* qr = Qg0 + ((size_t)bh * LL + m0 + w * 32 + j31) * DD + h * 8;
#pragma unroll
        for (int ks = 0; ks < 4; ++ks) {
            f32x4 a = *(const f32x4*)(qr + ks * 16);
            f32x4 b = *(const f32x4*)(qr + ks * 16 + 4);
            u32x4 qp;
            qp[0] = cvt_pk_bf16(a[0], a[1]);
            qp[1] = cvt_pk_bf16(a[2], a[3]);
            qp[2] = cvt_pk_bf16(b[0], b[1]);
            qp[3] = cvt_pk_bf16(b[2], b[3]);
            qf[ks] = __builtin_bit_cast(s16x8, qp);
        }
    }

    // ---------- tile-0 staging + tile-1 register prefetch ----------
    const int kc = tid >> 3, kd = (tid & 7) * 8;     // K staging: key row, d base
    const int vc = tid & 63, vd = (tid >> 6) * 8;    // V staging: key col, d base
    f32x4 kvx, kvy, vvx, vvy;
    {
        const f32x4* s = (const f32x4*)(Kg + (size_t)kc * DD + kd);
        f32x4 x = s[0], y = s[1];
        u32x4 kp;
        kp[0] = cvt_pk_bf16(x[0], x[1]);
        kp[1] = cvt_pk_bf16(x[2], x[3]);
        kp[2] = cvt_pk_bf16(y[0], y[1]);
        kp[3] = cvt_pk_bf16(y[2], y[3]);
        *(u32x4*)&sm.Khi[0][kc][kd] = kp;
        const f32x4* s2 = (const f32x4*)(Vg + (size_t)vc * DD + vd);
        f32x4 vx = s2[0], vy = s2[1];
#pragma unroll
        for (int i = 0; i < 2; ++i) {
            u32 a0 = cvt_pk_bf16(vx[2 * i], vx[2 * i + 1]);
            sm.VT[0][vd + 2 * i][vc]     = (u16)a0;
            sm.VT[0][vd + 2 * i + 1][vc] = (u16)(a0 >> 16);
            u32 a1 = cvt_pk_bf16(vy[2 * i], vy[2 * i + 1]);
            sm.VT[0][vd + 4 + 2 * i][vc]     = (u16)a1;
            sm.VT[0][vd + 4 + 2 * i + 1][vc] = (u16)(a1 >> 16);
        }
    }
    {
        const f32x4* s = (const f32x4*)(Kg + (size_t)(64 + kc) * DD + kd);
        kvx = s[0]; kvy = s[1];
        const f32x4* s2 = (const f32x4*)(Vg + (size_t)(64 + vc) * DD + vd);
        vvx = s2[0]; vvy = s2[1];
    }
    float blo = -1.0e9f * (float)Mg[j31];
    float bhi = -1.0e9f * (float)Mg[32 + j31];
    float nlo = -1.0e9f * (float)Mg[64 + j31];
    float nhi = -1.0e9f * (float)Mg[96 + j31];

    f32x16 accO0, accO1;   // OUT[q=w*32+j31][d=regmap / +32], full keys (wave-local)
#pragma unroll
    for (int e = 0; e < 16; ++e) { accO0[e] = 0.0f; accO1[e] = 0.0f; }

    u16* spw = &sm.P[w][0][0];
    asm volatile("s_waitcnt lgkmcnt(0)" ::: "memory");
    __builtin_amdgcn_s_barrier();

    f32x16 dAlo, dAhi, dBlo, dBhi, dClo, dChi;   // quad-defer buffers

    for (int t4 = 0; t4 < NITER / 4; ++t4) {
#pragma unroll
        for (int p = 0; p < 4; ++p) {
            const int t = t4 * 4 + p;
            const int buf = p & 1;                // == t & 1 (t4*4 even)

            // ---- S = Q*K^T, both key halves (col=lane=key, row=query regmap) ----
            f32x16 aS0, aS1;
#pragma unroll
            for (int e = 0; e < 16; ++e) { aS0[e] = 0.0f; aS1[e] = 0.0f; }
#pragma unroll
            for (int ks = 0; ks < 4; ++ks) {
                s16x8 kf0 = *(const s16x8*)&sm.Khi[buf][j31][ks * 16 + h * 8];
                aS0 = __builtin_amdgcn_mfma_f32_32x32x16_bf16(qf[ks], kf0, aS0, 0, 0, 0);
                s16x8 kf1 = *(const s16x8*)&sm.Khi[buf][32 + j31][ks * 16 + h * 8];
                aS1 = __builtin_amdgcn_mfma_f32_32x32x16_bf16(qf[ks], kf1, aS1, 0, 0, 0);
            }

            // ---- softplus (both halves) + wave-private P write ----
            f32x16 plo, phi;
#pragma unroll
            for (int g = 0; g < 4; ++g) {
#pragma unroll
                for (int r = 0; r < 4; ++r) {
                    const int e = g * 4 + r;
                    float x0  = aS0[e] * 0.125f + blo;
                    float t0  = __builtin_amdgcn_exp2f(x0 * 1.44269504f);
                    plo[e] = __builtin_amdgcn_logf(1.0f + t0) * 3.38450771757785852e-4f;
                    float x1  = aS1[e] * 0.125f + bhi;
                    float t1  = __builtin_amdgcn_exp2f(x1 * 1.44269504f);
                    phi[e] = __builtin_amdgcn_logf(1.0f + t1) * 3.38450771757785852e-4f;
                    const int il = 8 * g + 4 * h + r;                  // local query row
                    spw[il * 72 + j31]      = (u16)cvt_pk_bf16(plo[e], plo[e]);
                    spw[il * 72 + 32 + j31] = (u16)cvt_pk_bf16(phi[e], phi[e]);
                }
            }

            // ---- quad-defer scores stores: 1KB/row single-wave bursts ----
            if (p == 0)      { dAlo = plo; dAhi = phi; }
            else if (p == 1) { dBlo = plo; dBhi = phi; }
            else if (p == 2) { dClo = plo; dChi = phi; }
            else {
                float* base = So + (size_t)(w * 32 + 4 * h) * LL + (size_t)(t4 * 4) * 64 + j31;
#pragma unroll
                for (int g = 0; g < 4; ++g)
#pragma unroll
                    for (int r = 0; r < 4; ++r) {
                        const int e = g * 4 + r;
                        float* ra = base + (size_t)(8 * g + r) * LL;
                        __builtin_nontemporal_store(dAlo[e], ra);
                        __builtin_nontemporal_store(dAhi[e], ra + 32);
                        __builtin_nontemporal_store(dBlo[e], ra + 64);
                        __builtin_nontemporal_store(dBhi[e], ra + 96);
                        __builtin_nontemporal_store(dClo[e], ra + 128);
                        __builtin_nontemporal_store(dChi[e], ra + 160);
                        __builtin_nontemporal_store(plo[e],  ra + 192);
                        __builtin_nontemporal_store(phi[e],  ra + 224);
                    }
            }
            asm volatile("s_waitcnt lgkmcnt(0)" ::: "memory");  // own P writes (same-wave)

            // ---- OUT += P*V over all 64 keys (wave-local, no barrier) ----
#pragma unroll
            for (int ks2 = 0; ks2 < 4; ++ks2) {
                s16x8 pb = *(const s16x8*)((const char*)spw + j31 * 144 + ks2 * 32 + h * 16);
                s16x8 va0 = *(const s16x8*)&sm.VT[buf][j31][ks2 * 16 + h * 8];
                accO0 = __builtin_amdgcn_mfma_f32_32x32x16_bf16(va0, pb, accO0, 0, 0, 0);
                s16x8 va1 = *(const s16x8*)&sm.VT[buf][32 + j31][ks2 * 16 + h * 8];
                accO1 = __builtin_amdgcn_mfma_f32_32x32x16_bf16(va1, pb, accO1, 0, 0, 0);
            }

            // ---- staging writes t+1 (regs -> other buffer) ----
            if (t + 1 < NITER) {
                u32x4 kp;
                kp[0] = cvt_pk_bf16(kvx[0], kvx[1]);
                kp[1] = cvt_pk_bf16(kvx[2], kvx[3]);
                kp[2] = cvt_pk_bf16(kvy[0], kvy[1]);
                kp[3] = cvt_pk_bf16(kvy[2], kvy[3]);
                *(u32x4*)&sm.Khi[buf ^ 1][kc][kd] = kp;
#pragma unroll
                for (int i = 0; i < 2; ++i) {
                    u32 a0 = cvt_pk_bf16(vvx[2 * i], vvx[2 * i + 1]);
                    sm.VT[buf ^ 1][vd + 2 * i][vc]     = (u16)a0;
                    sm.VT[buf ^ 1][vd + 2 * i + 1][vc] = (u16)(a0 >> 16);
                    u32 a1 = cvt_pk_bf16(vvy[2 * i], vvy[2 * i + 1]);
                    sm.VT[buf ^ 1][vd + 4 + 2 * i][vc]     = (u16)a1;
                    sm.VT[buf ^ 1][vd + 4 + 2 * i + 1][vc] = (u16)(a1 >> 16);
                }
            }
            // ---- prefetch tile t+2 into registers ----
            {
                const int tp = (t + 2 < NITER) ? (t + 2) : (NITER - 1);
                const f32x4* s1 = (const f32x4*)(Kg + (size_t)(tp * 64 + kc) * DD + kd);
                kvx = s1[0]; kvy = s1[1];
                const f32x4* s2 = (const f32x4*)(Vg + (size_t)(tp * 64 + vc) * DD + vd);
                vvx = s2[0]; vvy = s2[1];
                blo = nlo; bhi = nhi;
                nlo = -1.0e9f * (float)Mg[tp * 64 + j31];
                nhi = -1.0e9f * (float)Mg[tp * 64 + 32 + j31];
            }
            asm volatile("s_waitcnt lgkmcnt(0)" ::: "memory");  // staging visible; NT stores in flight
            __builtin_amdgcn_s_barrier();                        // one barrier per tile
        }
    }

    // ---- epilogue: direct store (wave-local, R5-validated mapping) ----
    float* op = Oo + (size_t)(w * 32 + j31) * DD;
#pragma unroll
    for (int db = 0; db < 2; ++db) {
        const f32x16& a = db ? accO1 : accO0;
#pragma unroll
        for (int g = 0; g < 4; ++g) {
            f32x4 o;
#pragma unroll
            for (int r = 0; r < 4; ++r) o[r] = a[g * 4 + r];
            *(f32x4*)(op + db * 32 + 8 * g + 4 * h) = o;
        }
    }
}

extern "C" void kernel_launch(void* const* d_in, const int* in_sizes, int n_in,
                              void* d_out, int out_size, void* d_ws, size_t ws_size,
                              hipStream_t stream) {
    const float* q    = (const float*)d_in[0];
    const float* k    = (const float*)d_in[1];
    const float* v    = (const float*)d_in[2];
    const int*   mask = (const int*)d_in[5];   // p_q, p_k unused by reference
    float* out = (float*)d_out;
    hipLaunchKernelGGL(psam_kernel, dim3(256), dim3(512), 0, stream, q, k, v, mask, out);
}